// Round 3
// baseline (307.255 us; speedup 1.0000x reference)
//
#include <hip/hip_runtime.h>
#include <math.h>

typedef short  short8  __attribute__((ext_vector_type(8)));
typedef short  short4v __attribute__((ext_vector_type(4)));
typedef float  f32x4   __attribute__((ext_vector_type(4)));

constexpr int D   = 1024;   // d_in = d_g
constexpr int K   = 512;    // codebook size
constexpr int BM  = 64;     // rows per block
constexpr int KP  = 256;    // k-panel (f32 elements)
constexpr float GAP_T = 2e-3f;   // ~400 sigma of 3-term split-bf16 noise

__device__ __forceinline__ unsigned short f2bf(float f) {
    unsigned u = __float_as_uint(f);
    u += 0x7FFFu + ((u >> 16) & 1u);          // round-to-nearest-even
    return (unsigned short)(u >> 16);
}
__device__ __forceinline__ float bf2f(unsigned short h) {
    return __uint_as_float(((unsigned)h) << 16);
}

// ---------------------------------------------------------------------------
// Kernel A: normalize codebook rows; emit bf16 hi/lo split + f32 copy.
// ---------------------------------------------------------------------------
__global__ __launch_bounds__(256)
void prep_codebook(const float* __restrict__ cb, unsigned short* __restrict__ cbh,
                   unsigned short* __restrict__ cbl, float* __restrict__ cff) {
    const int n = blockIdx.x, tid = threadIdx.x;
    const float4 v = reinterpret_cast<const float4*>(cb + (size_t)n * D)[tid];
    float ss = v.x*v.x + v.y*v.y + v.z*v.z + v.w*v.w;
#pragma unroll
    for (int off = 32; off > 0; off >>= 1) ss += __shfl_down(ss, off);
    __shared__ float wss[4];
    if ((tid & 63) == 0) wss[tid >> 6] = ss;
    __syncthreads();
    const float tot   = wss[0] + wss[1] + wss[2] + wss[3];
    const float scale = 1.0f / fmaxf(sqrtf(tot), 1e-12f);
    float f[4] = { v.x*scale, v.y*scale, v.z*scale, v.w*scale };
    float4 fv = { f[0], f[1], f[2], f[3] };
    reinterpret_cast<float4*>(cff + (size_t)n * D)[tid] = fv;
    unsigned short h[4], lo[4];
#pragma unroll
    for (int i = 0; i < 4; ++i) { h[i] = f2bf(f[i]); lo[i] = f2bf(f[i] - bf2f(h[i])); }
    short4v hv = { (short)h[0], (short)h[1], (short)h[2], (short)h[3] };
    short4v lv = { (short)lo[0], (short)lo[1], (short)lo[2], (short)lo[3] };
    *reinterpret_cast<short4v*>(cbh + (size_t)n * D + tid * 4) = hv;
    *reinterpret_cast<short4v*>(cbl + (size_t)n * D + tid * 4) = lv;
}

// ---------------------------------------------------------------------------
// Kernel B: 3-product split-bf16 MFMA GEMM + top-2 argmax + flag + epilogue.
// 512 threads = 8 waves; wave w owns codes [w*64, w*64+64) -> nt = 4 tiles.
// Per wave: 4 m-tiles x 4 n-tiles of mfma_f32_16x16x32_bf16, 3 products each.
// ---------------------------------------------------------------------------
__global__ __launch_bounds__(512, 1)
void vq_mfma(const float* __restrict__ z, const float* __restrict__ tgt,
             const unsigned short* __restrict__ cbh,
             const unsigned short* __restrict__ cbl,
             const float* __restrict__ E, float* __restrict__ out,
             int* __restrict__ flags) {
    __shared__ alignas(16) unsigned char AhB[BM * KP * 2];   // 32 KB, swizzled bf16 hi
    __shared__ alignas(16) unsigned char AlB[BM * KP * 2];   // 32 KB, swizzled bf16 lo
    __shared__ float cv1[8][BM];
    __shared__ float cv2[8][BM];
    __shared__ int   ci1[8][BM];
    __shared__ int   bestk_s[BM];

    const int tid = threadIdx.x;
    const int r0  = blockIdx.x * BM;
    const int l   = tid & 63;
    const int wv  = tid >> 6;        // 0..7
    const int lr  = l & 15;          // row-in-tile (A) / col-in-tile (B,D)
    const int lg  = l >> 4;          // k-group

    f32x4 acc[4][4];
#pragma unroll
    for (int m = 0; m < 4; ++m)
#pragma unroll
        for (int nt = 0; nt < 4; ++nt) acc[m][nt] = (f32x4){0.f, 0.f, 0.f, 0.f};

    const int aswz = (lr & 7) << 4;
    const short8* bh8 = reinterpret_cast<const short8*>(cbh) + (size_t)(wv*64 + lr) * 128 + lg;
    const short8* bl8 = reinterpret_cast<const short8*>(cbl) + (size_t)(wv*64 + lr) * 128 + lg;

    for (int p = 0; p < 4; ++p) {
        if (p) __syncthreads();
        // ---- stage z panel [64 rows][256 cols] -> bf16 hi/lo, swizzled ----
#pragma unroll
        for (int c = 0; c < 8; ++c) {
            const int idx = tid + 512 * c;   // 0..4095
            const int row = idx >> 6;        // 0..63
            const int c4  = idx & 63;        // float4 within row
            const float4 v = reinterpret_cast<const float4*>(
                z + (size_t)(r0 + row) * D + p * KP)[c4];
            unsigned short h0 = f2bf(v.x), h1 = f2bf(v.y), h2 = f2bf(v.z), h3 = f2bf(v.w);
            short4v hv = { (short)h0, (short)h1, (short)h2, (short)h3 };
            short4v lv = { (short)f2bf(v.x - bf2f(h0)), (short)f2bf(v.y - bf2f(h1)),
                           (short)f2bf(v.z - bf2f(h2)), (short)f2bf(v.w - bf2f(h3)) };
            const int ad = (row * 512 + c4 * 8) ^ ((row & 7) << 4);
            *reinterpret_cast<short4v*>(AhB + ad) = hv;
            *reinterpret_cast<short4v*>(AlB + ad) = lv;
        }
        __syncthreads();
        // ---- MFMA over this panel: 8 k-steps of 32 ----
#pragma unroll 2
        for (int ks = 0; ks < 8; ++ks) {
            short8 ah[4], al[4];
#pragma unroll
            for (int m = 0; m < 4; ++m) {
                const int ad = ((m * 16 + lr) * 512 + lg * 16 + ks * 64) ^ aswz;
                ah[m] = *reinterpret_cast<const short8*>(AhB + ad);
                al[m] = *reinterpret_cast<const short8*>(AlB + ad);
            }
#pragma unroll
            for (int nt = 0; nt < 4; ++nt) {
                const int bo = nt * 2048 + p * 32 + ks * 4;
                const short8 bh = bh8[bo];
                const short8 bl = bl8[bo];
#pragma unroll
                for (int m = 0; m < 4; ++m) {
                    acc[m][nt] = __builtin_amdgcn_mfma_f32_16x16x32_bf16(ah[m], bh, acc[m][nt], 0, 0, 0);
                    acc[m][nt] = __builtin_amdgcn_mfma_f32_16x16x32_bf16(ah[m], bl, acc[m][nt], 0, 0, 0);
                    acc[m][nt] = __builtin_amdgcn_mfma_f32_16x16x32_bf16(al[m], bh, acc[m][nt], 0, 0, 0);
                }
            }
        }
    }

    // ---- top-2 per row: in-register nt scan, 16-lane butterfly, wave merge ----
    // D layout: acc[m][nt][r] = logits[row = m*16 + lg*4 + r][col = wv*64 + nt*16 + lr]
#pragma unroll
    for (int m = 0; m < 4; ++m)
#pragma unroll
        for (int r = 0; r < 4; ++r) {
            float v1 = acc[m][0][r];
            int   i1 = wv * 64 + lr;
            float v2 = -INFINITY;
#pragma unroll
            for (int nt = 1; nt < 4; ++nt) {
                const float v = acc[m][nt][r];
                const int   n = wv * 64 + nt * 16 + lr;
                if (v > v1) { v2 = v1; v1 = v; i1 = n; }
                else        { v2 = fmaxf(v2, v); }
            }
#pragma unroll
            for (int msk = 1; msk < 16; msk <<= 1) {
                const float ov1 = __shfl_xor(v1, msk);
                const float ov2 = __shfl_xor(v2, msk);
                const int   oi1 = __shfl_xor(i1, msk);
                if (ov1 > v1 || (ov1 == v1 && oi1 < i1)) { v2 = fmaxf(v1, ov2); v1 = ov1; i1 = oi1; }
                else                                     { v2 = fmaxf(v2, ov1); }
            }
            if (lr == 0) {
                const int row = m * 16 + lg * 4 + r;
                cv1[wv][row] = v1; cv2[wv][row] = v2; ci1[wv][row] = i1;
            }
        }
    __syncthreads();
    if (tid < BM) {
        float v1 = cv1[0][tid], v2 = cv2[0][tid];
        int   i1 = ci1[0][tid];
        for (int w = 1; w < 8; ++w) {
            const float a1 = cv1[w][tid], a2 = cv2[w][tid];
            const int   b1 = ci1[w][tid];
            if (a1 > v1 || (a1 == v1 && b1 < i1)) { v2 = fmaxf(v1, a2); v1 = a1; i1 = b1; }
            else                                  { v2 = fmaxf(v2, a1); }
        }
        bestk_s[tid] = i1;
        flags[r0 + tid] = (v1 - v2 < GAP_T) ? 1 : 0;
    }
    __syncthreads();

    // ---- epilogue: out = target * (1 + E[best]); two rows per iteration ----
    const int erow = tid >> 8;       // 0 or 1
    const int ecol = tid & 255;      // float4 index within row
#pragma unroll 4
    for (int t = 0; t < 32; ++t) {
        const int row = t * 2 + erow;
        const int bi  = bestk_s[row];
        const float4 tv = reinterpret_cast<const float4*>(tgt + (size_t)(r0 + row) * D)[ecol];
        const float4 ev = reinterpret_cast<const float4*>(E + (size_t)bi * D)[ecol];
        float4 o;
        o.x = tv.x * (1.0f + ev.x);
        o.y = tv.y * (1.0f + ev.y);
        o.z = tv.z * (1.0f + ev.z);
        o.w = tv.w * (1.0f + ev.w);
        reinterpret_cast<float4*>(out + (size_t)(r0 + row) * D)[ecol] = o;
    }
}

// ---------------------------------------------------------------------------
// Kernel C: exact f32 rescue for flagged rows (rare). Recompute argmax +
// rewrite the output row.
// ---------------------------------------------------------------------------
__global__ __launch_bounds__(256)
void vq_rescue(const float* __restrict__ z, const float* __restrict__ tgt,
               const float* __restrict__ cff, const float* __restrict__ E,
               const int* __restrict__ flags, float* __restrict__ out) {
    __shared__ int   rowf[BM];
    __shared__ int   anyf;
    __shared__ float bv[256];
    __shared__ int   bidx[256];
    const int tid = threadIdx.x;
    const int r0  = blockIdx.x * BM;
    if (tid == 0) anyf = 0;
    if (tid < BM) rowf[tid] = flags[r0 + tid];
    __syncthreads();
    if (tid < BM && rowf[tid]) anyf = 1;   // benign race, all write 1
    __syncthreads();
    if (!anyf) return;

    for (int t = 0; t < BM; ++t) {
        if (!rowf[t]) continue;            // uniform branch
        const int row = r0 + t;
        const float4* zr = reinterpret_cast<const float4*>(z + (size_t)row * D);
        const float4* c1 = reinterpret_cast<const float4*>(cff + (size_t)tid * D);
        const float4* c2 = reinterpret_cast<const float4*>(cff + (size_t)(tid + 256) * D);
        float4 s1 = {0.f, 0.f, 0.f, 0.f}, s2 = {0.f, 0.f, 0.f, 0.f};
        for (int d = 0; d < D / 4; ++d) {
            const float4 a = zr[d];
            const float4 x = c1[d], y = c2[d];
            s1.x = fmaf(a.x, x.x, s1.x); s1.y = fmaf(a.y, x.y, s1.y);
            s1.z = fmaf(a.z, x.z, s1.z); s1.w = fmaf(a.w, x.w, s1.w);
            s2.x = fmaf(a.x, y.x, s2.x); s2.y = fmaf(a.y, y.y, s2.y);
            s2.z = fmaf(a.z, y.z, s2.z); s2.w = fmaf(a.w, y.w, s2.w);
        }
        const float v1 = (s1.x + s1.y) + (s1.z + s1.w);
        const float v2 = (s2.x + s2.y) + (s2.z + s2.w);
        float mv; int mi;
        if (v2 > v1) { mv = v2; mi = tid + 256; } else { mv = v1; mi = tid; }
        bv[tid] = mv; bidx[tid] = mi;
        __syncthreads();
        for (int s = 128; s > 0; s >>= 1) {
            if (tid < s) {
                if (bv[tid + s] > bv[tid] ||
                    (bv[tid + s] == bv[tid] && bidx[tid + s] < bidx[tid])) {
                    bv[tid] = bv[tid + s]; bidx[tid] = bidx[tid + s];
                }
            }
            __syncthreads();
        }
        const int best = bidx[0];
        __syncthreads();
        const float4 tv = reinterpret_cast<const float4*>(tgt + (size_t)row * D)[tid];
        const float4 ev = reinterpret_cast<const float4*>(E + (size_t)best * D)[tid];
        float4 o;
        o.x = tv.x * (1.0f + ev.x);
        o.y = tv.y * (1.0f + ev.y);
        o.z = tv.z * (1.0f + ev.z);
        o.w = tv.w * (1.0f + ev.w);
        reinterpret_cast<float4*>(out + (size_t)row * D)[tid] = o;
        __syncthreads();
    }
}

extern "C" void kernel_launch(void* const* d_in, const int* in_sizes, int n_in,
                              void* d_out, int out_size, void* d_ws, size_t ws_size,
                              hipStream_t stream) {
    const float* z        = (const float*)d_in[0];
    const float* target   = (const float*)d_in[1];
    const float* codebook = (const float*)d_in[2];
    const float* E        = (const float*)d_in[3];
    float* out = (float*)d_out;

    unsigned short* cbh = (unsigned short*)d_ws;            // 1 MB
    unsigned short* cbl = cbh + (size_t)K * D;              // 1 MB
    float*          cff = (float*)(cbl + (size_t)K * D);    // 2 MB
    int*            flg = (int*)(cff + (size_t)K * D);      // 64 KB

    const int rows = in_sizes[0] / D;                       // 16384
    hipLaunchKernelGGL(prep_codebook, dim3(K), dim3(256), 0, stream,
                       codebook, cbh, cbl, cff);
    hipLaunchKernelGGL(vq_mfma, dim3(rows / BM), dim3(512), 0, stream,
                       z, target, cbh, cbl, E, out, flg);
    hipLaunchKernelGGL(vq_rescue, dim3(rows / BM), dim3(256), 0, stream,
                       z, target, cff, E, flg, out);
}

// Round 4
// 228.303 us; speedup vs baseline: 1.3458x; 1.3458x over previous
//
#include <hip/hip_runtime.h>
#include <math.h>

typedef short  short8  __attribute__((ext_vector_type(8)));
typedef short  short4v __attribute__((ext_vector_type(4)));
typedef float  f32x4   __attribute__((ext_vector_type(4)));

constexpr int D   = 1024;   // d_in = d_g
constexpr int K   = 512;    // codebook size
constexpr int BM  = 64;     // rows per block (vq_mfma)
constexpr int KP  = 256;    // k-panel (f32 elements)
constexpr float GAP_T = 2e-3f;   // ~400 sigma of 3-term split-bf16 noise

__device__ __forceinline__ unsigned short f2bf(float f) {
    unsigned u = __float_as_uint(f);
    u += 0x7FFFu + ((u >> 16) & 1u);          // round-to-nearest-even
    return (unsigned short)(u >> 16);
}
__device__ __forceinline__ float bf2f(unsigned short h) {
    return __uint_as_float(((unsigned)h) << 16);
}

// ---------------------------------------------------------------------------
// Kernel A: normalize codebook rows; emit bf16 hi/lo split + f32 copy.
// ---------------------------------------------------------------------------
__global__ __launch_bounds__(256)
void prep_codebook(const float* __restrict__ cb, unsigned short* __restrict__ cbh,
                   unsigned short* __restrict__ cbl, float* __restrict__ cff) {
    const int n = blockIdx.x, tid = threadIdx.x;
    const float4 v = reinterpret_cast<const float4*>(cb + (size_t)n * D)[tid];
    float ss = v.x*v.x + v.y*v.y + v.z*v.z + v.w*v.w;
#pragma unroll
    for (int off = 32; off > 0; off >>= 1) ss += __shfl_down(ss, off);
    __shared__ float wss[4];
    if ((tid & 63) == 0) wss[tid >> 6] = ss;
    __syncthreads();
    const float tot   = wss[0] + wss[1] + wss[2] + wss[3];
    const float scale = 1.0f / fmaxf(sqrtf(tot), 1e-12f);
    float f[4] = { v.x*scale, v.y*scale, v.z*scale, v.w*scale };
    float4 fv = { f[0], f[1], f[2], f[3] };
    reinterpret_cast<float4*>(cff + (size_t)n * D)[tid] = fv;
    unsigned short h[4], lo[4];
#pragma unroll
    for (int i = 0; i < 4; ++i) { h[i] = f2bf(f[i]); lo[i] = f2bf(f[i] - bf2f(h[i])); }
    short4v hv = { (short)h[0], (short)h[1], (short)h[2], (short)h[3] };
    short4v lv = { (short)lo[0], (short)lo[1], (short)lo[2], (short)lo[3] };
    *reinterpret_cast<short4v*>(cbh + (size_t)n * D + tid * 4) = hv;
    *reinterpret_cast<short4v*>(cbl + (size_t)n * D + tid * 4) = lv;
}

// ---------------------------------------------------------------------------
// Kernel B: 3-product split-bf16 MFMA GEMM + top-2 argmax + flag + epilogue.
// 512 threads = 8 waves; wave w owns codes [w*64, w*64+64) -> nt = 4 tiles.
// Per wave: 4 m-tiles x 4 n-tiles of mfma_f32_16x16x32_bf16, 3 products each.
// ---------------------------------------------------------------------------
__global__ __launch_bounds__(512, 4)   // pin VGPR <= 128 -> 2 blocks/CU
void vq_mfma(const float* __restrict__ z, const float* __restrict__ tgt,
             const unsigned short* __restrict__ cbh,
             const unsigned short* __restrict__ cbl,
             const float* __restrict__ E, float* __restrict__ out,
             int* __restrict__ flags) {
    __shared__ alignas(16) unsigned char AhB[BM * KP * 2];   // 32 KB, swizzled bf16 hi
    __shared__ alignas(16) unsigned char AlB[BM * KP * 2];   // 32 KB, swizzled bf16 lo
    __shared__ float cv1[8][BM];
    __shared__ float cv2[8][BM];
    __shared__ int   ci1[8][BM];
    __shared__ int   bestk_s[BM];

    const int tid = threadIdx.x;
    const int r0  = blockIdx.x * BM;
    const int l   = tid & 63;
    const int wv  = tid >> 6;        // 0..7
    const int lr  = l & 15;          // row-in-tile (A) / col-in-tile (B,D)
    const int lg  = l >> 4;          // k-group

    f32x4 acc[4][4];
#pragma unroll
    for (int m = 0; m < 4; ++m)
#pragma unroll
        for (int nt = 0; nt < 4; ++nt) acc[m][nt] = (f32x4){0.f, 0.f, 0.f, 0.f};

    const int aswz = (lr & 7) << 4;
    const short8* bh8 = reinterpret_cast<const short8*>(cbh) + (size_t)(wv*64 + lr) * 128 + lg;
    const short8* bl8 = reinterpret_cast<const short8*>(cbl) + (size_t)(wv*64 + lr) * 128 + lg;

    for (int p = 0; p < 4; ++p) {
        if (p) __syncthreads();
        // ---- stage z panel [64 rows][256 cols] -> bf16 hi/lo, swizzled ----
#pragma unroll
        for (int c = 0; c < 8; ++c) {
            const int idx = tid + 512 * c;   // 0..4095
            const int row = idx >> 6;        // 0..63
            const int c4  = idx & 63;        // float4 within row
            const float4 v = reinterpret_cast<const float4*>(
                z + (size_t)(r0 + row) * D + p * KP)[c4];
            unsigned short h0 = f2bf(v.x), h1 = f2bf(v.y), h2 = f2bf(v.z), h3 = f2bf(v.w);
            short4v hv = { (short)h0, (short)h1, (short)h2, (short)h3 };
            short4v lv = { (short)f2bf(v.x - bf2f(h0)), (short)f2bf(v.y - bf2f(h1)),
                           (short)f2bf(v.z - bf2f(h2)), (short)f2bf(v.w - bf2f(h3)) };
            const int ad = (row * 512 + c4 * 8) ^ ((row & 7) << 4);
            *reinterpret_cast<short4v*>(AhB + ad) = hv;
            *reinterpret_cast<short4v*>(AlB + ad) = lv;
        }
        __syncthreads();
        // ---- MFMA over this panel: 8 k-steps of 32 ----
#pragma unroll 2
        for (int ks = 0; ks < 8; ++ks) {
            short8 ah[4], al[4];
#pragma unroll
            for (int m = 0; m < 4; ++m) {
                const int ad = ((m * 16 + lr) * 512 + lg * 16 + ks * 64) ^ aswz;
                ah[m] = *reinterpret_cast<const short8*>(AhB + ad);
                al[m] = *reinterpret_cast<const short8*>(AlB + ad);
            }
#pragma unroll
            for (int nt = 0; nt < 4; ++nt) {
                const int bo = nt * 2048 + p * 32 + ks * 4;
                const short8 bh = bh8[bo];
                const short8 bl = bl8[bo];
#pragma unroll
                for (int m = 0; m < 4; ++m) {
                    acc[m][nt] = __builtin_amdgcn_mfma_f32_16x16x32_bf16(ah[m], bh, acc[m][nt], 0, 0, 0);
                    acc[m][nt] = __builtin_amdgcn_mfma_f32_16x16x32_bf16(ah[m], bl, acc[m][nt], 0, 0, 0);
                    acc[m][nt] = __builtin_amdgcn_mfma_f32_16x16x32_bf16(al[m], bh, acc[m][nt], 0, 0, 0);
                }
            }
        }
    }

    // ---- top-2 per row: in-register nt scan, 16-lane butterfly, wave merge ----
    // D layout: acc[m][nt][r] = logits[row = m*16 + lg*4 + r][col = wv*64 + nt*16 + lr]
#pragma unroll
    for (int m = 0; m < 4; ++m)
#pragma unroll
        for (int r = 0; r < 4; ++r) {
            float v1 = acc[m][0][r];
            int   i1 = wv * 64 + lr;
            float v2 = -INFINITY;
#pragma unroll
            for (int nt = 1; nt < 4; ++nt) {
                const float v = acc[m][nt][r];
                const int   n = wv * 64 + nt * 16 + lr;
                if (v > v1) { v2 = v1; v1 = v; i1 = n; }
                else        { v2 = fmaxf(v2, v); }
            }
#pragma unroll
            for (int msk = 1; msk < 16; msk <<= 1) {
                const float ov1 = __shfl_xor(v1, msk);
                const float ov2 = __shfl_xor(v2, msk);
                const int   oi1 = __shfl_xor(i1, msk);
                if (ov1 > v1 || (ov1 == v1 && oi1 < i1)) { v2 = fmaxf(v1, ov2); v1 = ov1; i1 = oi1; }
                else                                     { v2 = fmaxf(v2, ov1); }
            }
            if (lr == 0) {
                const int row = m * 16 + lg * 4 + r;
                cv1[wv][row] = v1; cv2[wv][row] = v2; ci1[wv][row] = i1;
            }
        }
    __syncthreads();
    if (tid < BM) {
        float v1 = cv1[0][tid], v2 = cv2[0][tid];
        int   i1 = ci1[0][tid];
        for (int w = 1; w < 8; ++w) {
            const float a1 = cv1[w][tid], a2 = cv2[w][tid];
            const int   b1 = ci1[w][tid];
            if (a1 > v1 || (a1 == v1 && b1 < i1)) { v2 = fmaxf(v1, a2); v1 = a1; i1 = b1; }
            else                                  { v2 = fmaxf(v2, a1); }
        }
        bestk_s[tid] = i1;
        flags[r0 + tid] = (v1 - v2 < GAP_T) ? 1 : 0;
    }
    __syncthreads();

    // ---- epilogue: out = target * (1 + E[best]); two rows per iteration ----
    const int erow = tid >> 8;       // 0 or 1
    const int ecol = tid & 255;      // float4 index within row
#pragma unroll 4
    for (int t = 0; t < 32; ++t) {
        const int row = t * 2 + erow;
        const int bi  = bestk_s[row];
        const float4 tv = reinterpret_cast<const float4*>(tgt + (size_t)(r0 + row) * D)[ecol];
        const float4 ev = reinterpret_cast<const float4*>(E + (size_t)bi * D)[ecol];
        float4 o;
        o.x = tv.x * (1.0f + ev.x);
        o.y = tv.y * (1.0f + ev.y);
        o.z = tv.z * (1.0f + ev.z);
        o.w = tv.w * (1.0f + ev.w);
        reinterpret_cast<float4*>(out + (size_t)(r0 + row) * D)[ecol] = o;
    }
}

// ---------------------------------------------------------------------------
// Kernel C: exact f32 rescue, ONE BLOCK PER ROW (grid = 16384). 99.4% of
// blocks exit after one uniform flag load. Flagged rows: z row in LDS, each
// of 4 waves sweeps 128 codes with coalesced float4 reads + shfl reduce.
// ---------------------------------------------------------------------------
__global__ __launch_bounds__(256)
void vq_rescue(const float* __restrict__ z, const float* __restrict__ tgt,
               const float* __restrict__ cff, const float* __restrict__ E,
               const int* __restrict__ flags, float* __restrict__ out) {
    const int row = blockIdx.x;
    if (!flags[row]) return;

    const int tid = threadIdx.x;
    const int l   = tid & 63;
    const int wv  = tid >> 6;        // 0..3
    __shared__ float zs[D];
    __shared__ float wvv[4];
    __shared__ int   wvi[4];

    reinterpret_cast<float4*>(zs)[tid] =
        reinterpret_cast<const float4*>(z + (size_t)row * D)[tid];
    __syncthreads();

    float v1 = -INFINITY;
    int   i1 = 0;
#pragma unroll 4
    for (int kk = 0; kk < 128; ++kk) {
        const int k = wv * 128 + kk;
        const float4* cr = reinterpret_cast<const float4*>(cff + (size_t)k * D);
        float s = 0.f;
#pragma unroll
        for (int j = 0; j < 4; ++j) {
            const float4 c = cr[j * 64 + l];               // coalesced: 64 lanes x 16B
            const float4 a = *reinterpret_cast<const float4*>(zs + j * 256 + l * 4);
            s = fmaf(c.x, a.x, s); s = fmaf(c.y, a.y, s);
            s = fmaf(c.z, a.z, s); s = fmaf(c.w, a.w, s);
        }
#pragma unroll
        for (int off = 32; off > 0; off >>= 1) s += __shfl_xor(s, off);
        if (s > v1) { v1 = s; i1 = k; }   // ascending k + strict > = first-index ties
    }
    if (l == 0) { wvv[wv] = v1; wvi[wv] = i1; }
    __syncthreads();
    if (tid == 0) {
        float bv = wvv[0]; int bi = wvi[0];
        for (int w = 1; w < 4; ++w) {
            if (wvv[w] > bv || (wvv[w] == bv && wvi[w] < bi)) { bv = wvv[w]; bi = wvi[w]; }
        }
        wvi[0] = bi;
    }
    __syncthreads();
    const int best = wvi[0];

    const float4 tv = reinterpret_cast<const float4*>(tgt + (size_t)row * D)[tid];
    const float4 ev = reinterpret_cast<const float4*>(E + (size_t)best * D)[tid];
    float4 o;
    o.x = tv.x * (1.0f + ev.x);
    o.y = tv.y * (1.0f + ev.y);
    o.z = tv.z * (1.0f + ev.z);
    o.w = tv.w * (1.0f + ev.w);
    reinterpret_cast<float4*>(out + (size_t)row * D)[tid] = o;
}

extern "C" void kernel_launch(void* const* d_in, const int* in_sizes, int n_in,
                              void* d_out, int out_size, void* d_ws, size_t ws_size,
                              hipStream_t stream) {
    const float* z        = (const float*)d_in[0];
    const float* target   = (const float*)d_in[1];
    const float* codebook = (const float*)d_in[2];
    const float* E        = (const float*)d_in[3];
    float* out = (float*)d_out;

    unsigned short* cbh = (unsigned short*)d_ws;            // 1 MB
    unsigned short* cbl = cbh + (size_t)K * D;              // 1 MB
    float*          cff = (float*)(cbl + (size_t)K * D);    // 2 MB
    int*            flg = (int*)(cff + (size_t)K * D);      // 64 KB

    const int rows = in_sizes[0] / D;                       // 16384
    hipLaunchKernelGGL(prep_codebook, dim3(K), dim3(256), 0, stream,
                       codebook, cbh, cbl, cff);
    hipLaunchKernelGGL(vq_mfma, dim3(rows / BM), dim3(512), 0, stream,
                       z, target, cbh, cbl, E, out, flg);
    hipLaunchKernelGGL(vq_rescue, dim3(rows), dim3(256), 0, stream,
                       z, target, cff, E, flg, out);
}

// Round 5
// 159.392 us; speedup vs baseline: 1.9277x; 1.4323x over previous
//
#include <hip/hip_runtime.h>
#include <math.h>

typedef short  short8  __attribute__((ext_vector_type(8)));
typedef short  short4v __attribute__((ext_vector_type(4)));
typedef float  f32x4   __attribute__((ext_vector_type(4)));

constexpr int D   = 1024;   // d_in = d_g
constexpr int K   = 512;    // codebook size
constexpr int BM  = 64;     // rows per block (vq_mfma)
constexpr int KP  = 256;    // k-panel (f32 elements)
constexpr float GAP_T = 2e-3f;   // ~400 sigma of 3-term split-bf16 noise

__device__ __forceinline__ unsigned short f2bf(float f) {
    unsigned u = __float_as_uint(f);
    u += 0x7FFFu + ((u >> 16) & 1u);          // round-to-nearest-even
    return (unsigned short)(u >> 16);
}
__device__ __forceinline__ float bf2f(unsigned short h) {
    return __uint_as_float(((unsigned)h) << 16);
}

// ---------------------------------------------------------------------------
// Kernel A: normalize codebook rows; emit MFMA-fragment-packed bf16 hi/lo
// (cbp) + f32 copy (cff, for rescue).
// Packed layout, short8 (16B) units: fragment fi = ((code>>4)*32 + (k>>5))*2 + h
// holds 64 lanes x 16B; lane l = (k-octet lg = l>>4)*16 + (code lr = l&15);
// lane data = codes[base+lr][kstep*32 + lg*8 .. +8].
// ---------------------------------------------------------------------------
__global__ __launch_bounds__(256)
void prep_codebook(const float* __restrict__ cb, unsigned short* __restrict__ cbp,
                   float* __restrict__ cff) {
    const int n = blockIdx.x, tid = threadIdx.x;
    const float4 v = reinterpret_cast<const float4*>(cb + (size_t)n * D)[tid];
    float ss = v.x*v.x + v.y*v.y + v.z*v.z + v.w*v.w;
#pragma unroll
    for (int off = 32; off > 0; off >>= 1) ss += __shfl_down(ss, off);
    __shared__ float wss[4];
    if ((tid & 63) == 0) wss[tid >> 6] = ss;
    __syncthreads();
    const float tot   = wss[0] + wss[1] + wss[2] + wss[3];
    const float scale = 1.0f / fmaxf(sqrtf(tot), 1e-12f);
    float f[4] = { v.x*scale, v.y*scale, v.z*scale, v.w*scale };
    float4 fv = { f[0], f[1], f[2], f[3] };
    reinterpret_cast<float4*>(cff + (size_t)n * D)[tid] = fv;

    unsigned short h[4], lo[4];
#pragma unroll
    for (int i = 0; i < 4; ++i) { h[i] = f2bf(f[i]); lo[i] = f2bf(f[i] - bf2f(h[i])); }
    short4v hv = { (short)h[0], (short)h[1], (short)h[2], (short)h[3] };
    short4v lv = { (short)lo[0], (short)lo[1], (short)lo[2], (short)lo[3] };

    // thread tid covers k0 = tid*4 .. +4 of code n
    const int nt_g = n >> 4;           // 0..31
    const int lr   = n & 15;
    const int ks_g = tid >> 3;         // 0..31
    const int lg   = (tid >> 1) & 3;
    const int half = tid & 1;
    const size_t fbase = ((size_t)(nt_g * 32 + ks_g) * 2) * 1024;   // bytes
    unsigned char* base = (unsigned char*)cbp;
    *reinterpret_cast<short4v*>(base + fbase + (lg * 16 + lr) * 16 + half * 8) = hv;
    *reinterpret_cast<short4v*>(base + fbase + 1024 + (lg * 16 + lr) * 16 + half * 8) = lv;
}

// ---------------------------------------------------------------------------
// Kernel B: 3-product split-bf16 MFMA GEMM + top-2 argmax + flag + epilogue.
// 512 threads = 8 waves; wave w owns codes [w*64, w*64+64) -> nt = 4 tiles.
// B fragments are pre-packed -> one coalesced 1KB load per fragment, and
// software-pipelined one k-step ahead in registers.
// ---------------------------------------------------------------------------
__global__ __launch_bounds__(512, 2)
void vq_mfma(const float* __restrict__ z, const float* __restrict__ tgt,
             const unsigned short* __restrict__ cbp,
             const float* __restrict__ E, float* __restrict__ out,
             int* __restrict__ flags) {
    __shared__ alignas(16) unsigned char AhB[BM * KP * 2];   // 32 KB, swizzled bf16 hi
    __shared__ alignas(16) unsigned char AlB[BM * KP * 2];   // 32 KB, swizzled bf16 lo
    __shared__ float cv1[8][BM];
    __shared__ float cv2[8][BM];
    __shared__ int   ci1[8][BM];
    __shared__ int   bestk_s[BM];

    const int tid = threadIdx.x;
    const int r0  = blockIdx.x * BM;
    const int l   = tid & 63;
    const int wv  = tid >> 6;        // 0..7
    const int lr  = l & 15;          // row-in-tile (A) / col-in-tile (B,D)
    const int lg  = l >> 4;          // k-group

    f32x4 acc[4][4];
#pragma unroll
    for (int m = 0; m < 4; ++m)
#pragma unroll
        for (int nt = 0; nt < 4; ++nt) acc[m][nt] = (f32x4){0.f, 0.f, 0.f, 0.f};

    const int aswz = (lr & 7) << 4;
    // per-lane pointer into packed B: fragment fi -> bp[fi*64 + l]
    const short8* bp = reinterpret_cast<const short8*>(cbp) + l;

    for (int p = 0; p < 4; ++p) {
        if (p) __syncthreads();
        // ---- stage z panel [64 rows][256 cols] -> bf16 hi/lo, swizzled ----
#pragma unroll
        for (int c = 0; c < 8; ++c) {
            const int idx = tid + 512 * c;   // 0..4095
            const int row = idx >> 6;        // 0..63
            const int c4  = idx & 63;        // float4 within row
            const float4 v = reinterpret_cast<const float4*>(
                z + (size_t)(r0 + row) * D + p * KP)[c4];
            unsigned short h0 = f2bf(v.x), h1 = f2bf(v.y), h2 = f2bf(v.z), h3 = f2bf(v.w);
            short4v hv = { (short)h0, (short)h1, (short)h2, (short)h3 };
            short4v lv = { (short)f2bf(v.x - bf2f(h0)), (short)f2bf(v.y - bf2f(h1)),
                           (short)f2bf(v.z - bf2f(h2)), (short)f2bf(v.w - bf2f(h3)) };
            const int ad = (row * 512 + c4 * 8) ^ ((row & 7) << 4);
            *reinterpret_cast<short4v*>(AhB + ad) = hv;
            *reinterpret_cast<short4v*>(AlB + ad) = lv;
        }
        __syncthreads();

        // ---- MFMA over this panel: 8 k-steps of 32, B double-buffered ----
        short8 bb[2][4][2];
#pragma unroll
        for (int nt = 0; nt < 4; ++nt) {
            const size_t fi = ((size_t)((wv * 4 + nt) * 32 + p * 8) * 2);
            bb[0][nt][0] = bp[(fi + 0) * 64];
            bb[0][nt][1] = bp[(fi + 1) * 64];
        }
#pragma unroll
        for (int ks = 0; ks < 8; ++ks) {
            const int cur = ks & 1, nxt = cur ^ 1;
            if (ks < 7) {
#pragma unroll
                for (int nt = 0; nt < 4; ++nt) {
                    const size_t fi = ((size_t)((wv * 4 + nt) * 32 + p * 8 + ks + 1) * 2);
                    bb[nxt][nt][0] = bp[(fi + 0) * 64];
                    bb[nxt][nt][1] = bp[(fi + 1) * 64];
                }
            }
            short8 ah[4], al[4];
#pragma unroll
            for (int m = 0; m < 4; ++m) {
                const int ad = ((m * 16 + lr) * 512 + lg * 16 + ks * 64) ^ aswz;
                ah[m] = *reinterpret_cast<const short8*>(AhB + ad);
                al[m] = *reinterpret_cast<const short8*>(AlB + ad);
            }
#pragma unroll
            for (int nt = 0; nt < 4; ++nt) {
                const short8 bh = bb[cur][nt][0];
                const short8 bl = bb[cur][nt][1];
#pragma unroll
                for (int m = 0; m < 4; ++m) {
                    acc[m][nt] = __builtin_amdgcn_mfma_f32_16x16x32_bf16(ah[m], bh, acc[m][nt], 0, 0, 0);
                    acc[m][nt] = __builtin_amdgcn_mfma_f32_16x16x32_bf16(ah[m], bl, acc[m][nt], 0, 0, 0);
                    acc[m][nt] = __builtin_amdgcn_mfma_f32_16x16x32_bf16(al[m], bh, acc[m][nt], 0, 0, 0);
                }
            }
        }
    }

    // ---- top-2 per row: in-register nt scan, 16-lane butterfly, wave merge ----
    // D layout: acc[m][nt][r] = logits[row = m*16 + lg*4 + r][col = wv*64 + nt*16 + lr]
#pragma unroll
    for (int m = 0; m < 4; ++m)
#pragma unroll
        for (int r = 0; r < 4; ++r) {
            float v1 = acc[m][0][r];
            int   i1 = wv * 64 + lr;
            float v2 = -INFINITY;
#pragma unroll
            for (int nt = 1; nt < 4; ++nt) {
                const float v = acc[m][nt][r];
                const int   n = wv * 64 + nt * 16 + lr;
                if (v > v1) { v2 = v1; v1 = v; i1 = n; }
                else        { v2 = fmaxf(v2, v); }
            }
#pragma unroll
            for (int msk = 1; msk < 16; msk <<= 1) {
                const float ov1 = __shfl_xor(v1, msk);
                const float ov2 = __shfl_xor(v2, msk);
                const int   oi1 = __shfl_xor(i1, msk);
                if (ov1 > v1 || (ov1 == v1 && oi1 < i1)) { v2 = fmaxf(v1, ov2); v1 = ov1; i1 = oi1; }
                else                                     { v2 = fmaxf(v2, ov1); }
            }
            if (lr == 0) {
                const int row = m * 16 + lg * 4 + r;
                cv1[wv][row] = v1; cv2[wv][row] = v2; ci1[wv][row] = i1;
            }
        }
    __syncthreads();
    if (tid < BM) {
        float v1 = cv1[0][tid], v2 = cv2[0][tid];
        int   i1 = ci1[0][tid];
        for (int w = 1; w < 8; ++w) {
            const float a1 = cv1[w][tid], a2 = cv2[w][tid];
            const int   b1 = ci1[w][tid];
            if (a1 > v1 || (a1 == v1 && b1 < i1)) { v2 = fmaxf(v1, a2); v1 = a1; i1 = b1; }
            else                                  { v2 = fmaxf(v2, a1); }
        }
        bestk_s[tid] = i1;
        flags[r0 + tid] = (v1 - v2 < GAP_T) ? 1 : 0;
    }
    __syncthreads();

    // ---- epilogue: out = target * (1 + E[best]); two rows per iteration ----
    const int erow = tid >> 8;       // 0 or 1
    const int ecol = tid & 255;      // float4 index within row
#pragma unroll 4
    for (int t = 0; t < 32; ++t) {
        const int row = t * 2 + erow;
        const int bi  = bestk_s[row];
        const float4 tv = reinterpret_cast<const float4*>(tgt + (size_t)(r0 + row) * D)[ecol];
        const float4 ev = reinterpret_cast<const float4*>(E + (size_t)bi * D)[ecol];
        float4 o;
        o.x = tv.x * (1.0f + ev.x);
        o.y = tv.y * (1.0f + ev.y);
        o.z = tv.z * (1.0f + ev.z);
        o.w = tv.w * (1.0f + ev.w);
        reinterpret_cast<float4*>(out + (size_t)(r0 + row) * D)[ecol] = o;
    }
}

// ---------------------------------------------------------------------------
// Kernel C: exact f32 rescue, ONE BLOCK PER ROW (grid = 16384). 99.4% of
// blocks exit after one uniform flag load. Flagged rows: z row in LDS, each
// of 4 waves sweeps 128 codes with coalesced float4 reads + shfl reduce.
// ---------------------------------------------------------------------------
__global__ __launch_bounds__(256)
void vq_rescue(const float* __restrict__ z, const float* __restrict__ tgt,
               const float* __restrict__ cff, const float* __restrict__ E,
               const int* __restrict__ flags, float* __restrict__ out) {
    const int row = blockIdx.x;
    if (!flags[row]) return;

    const int tid = threadIdx.x;
    const int l   = tid & 63;
    const int wv  = tid >> 6;        // 0..3
    __shared__ float zs[D];
    __shared__ float wvv[4];
    __shared__ int   wvi[4];

    reinterpret_cast<float4*>(zs)[tid] =
        reinterpret_cast<const float4*>(z + (size_t)row * D)[tid];
    __syncthreads();

    float v1 = -INFINITY;
    int   i1 = 0;
#pragma unroll 4
    for (int kk = 0; kk < 128; ++kk) {
        const int k = wv * 128 + kk;
        const float4* cr = reinterpret_cast<const float4*>(cff + (size_t)k * D);
        float s = 0.f;
#pragma unroll
        for (int j = 0; j < 4; ++j) {
            const float4 c = cr[j * 64 + l];               // coalesced: 64 lanes x 16B
            const float4 a = *reinterpret_cast<const float4*>(zs + j * 256 + l * 4);
            s = fmaf(c.x, a.x, s); s = fmaf(c.y, a.y, s);
            s = fmaf(c.z, a.z, s); s = fmaf(c.w, a.w, s);
        }
#pragma unroll
        for (int off = 32; off > 0; off >>= 1) s += __shfl_xor(s, off);
        if (s > v1) { v1 = s; i1 = k; }   // ascending k + strict > = first-index ties
    }
    if (l == 0) { wvv[wv] = v1; wvi[wv] = i1; }
    __syncthreads();
    if (tid == 0) {
        float bv = wvv[0]; int bi = wvi[0];
        for (int w = 1; w < 4; ++w) {
            if (wvv[w] > bv || (wvv[w] == bv && wvi[w] < bi)) { bv = wvv[w]; bi = wvi[w]; }
        }
        wvi[0] = bi;
    }
    __syncthreads();
    const int best = wvi[0];

    const float4 tv = reinterpret_cast<const float4*>(tgt + (size_t)row * D)[tid];
    const float4 ev = reinterpret_cast<const float4*>(E + (size_t)best * D)[tid];
    float4 o;
    o.x = tv.x * (1.0f + ev.x);
    o.y = tv.y * (1.0f + ev.y);
    o.z = tv.z * (1.0f + ev.z);
    o.w = tv.w * (1.0f + ev.w);
    reinterpret_cast<float4*>(out + (size_t)row * D)[tid] = o;
}

extern "C" void kernel_launch(void* const* d_in, const int* in_sizes, int n_in,
                              void* d_out, int out_size, void* d_ws, size_t ws_size,
                              hipStream_t stream) {
    const float* z        = (const float*)d_in[0];
    const float* target   = (const float*)d_in[1];
    const float* codebook = (const float*)d_in[2];
    const float* E        = (const float*)d_in[3];
    float* out = (float*)d_out;

    unsigned short* cbp = (unsigned short*)d_ws;            // 2 MB packed hi/lo
    float*          cff = (float*)(cbp + (size_t)K * D * 2);// 2 MB f32
    int*            flg = (int*)(cff + (size_t)K * D);      // 64 KB

    const int rows = in_sizes[0] / D;                       // 16384
    hipLaunchKernelGGL(prep_codebook, dim3(K), dim3(256), 0, stream,
                       codebook, cbp, cff);
    hipLaunchKernelGGL(vq_mfma, dim3(rows / BM), dim3(512), 0, stream,
                       z, target, cbp, E, out, flg);
    hipLaunchKernelGGL(vq_rescue, dim3(rows), dim3(256), 0, stream,
                       z, target, cff, E, flg, out);
}